// Round 4
// baseline (356.562 us; speedup 1.0000x reference)
//
#include <hip/hip_runtime.h>

#define N_NODES 100000
#define N_EDGES 1000000

typedef __attribute__((ext_vector_type(8))) short bf16x8;
typedef __attribute__((ext_vector_type(4))) float f32x4;
typedef __attribute__((ext_vector_type(4))) unsigned u32x4;

static __device__ __forceinline__ short f2bf(float f) {
    unsigned u = __float_as_uint(f);
    u = (u + 0x7fffu + ((u >> 16) & 1u)) >> 16;
    return (short)u;
}
static __device__ __forceinline__ float bf2f(unsigned short s) {
    return __uint_as_float(((unsigned)s) << 16);
}
static __device__ __forceinline__ float lrelu(float x) {
    return fmaxf(x, 0.01f * x);   // 0.01x > x iff x < 0
}
// packed f32->bf16 (RNE)
static __device__ __forceinline__ unsigned cvtpk(float lo, float hi) {
    unsigned r;
    asm("v_cvt_pk_bf16_f32 %0, %1, %2" : "=v"(r) : "v"(lo), "v"(hi));
    return r;
}

// ---------------------------------------------------------------------------
// Precompute: P/Q as bf16 in gather-swizzled layout (unchanged).
// ---------------------------------------------------------------------------
__global__ __launch_bounds__(256) void precompute_mfma(
    const float* __restrict__ x, const float* __restrict__ W1,
    const float* __restrict__ b1, unsigned short* __restrict__ Pb,
    unsigned short* __restrict__ Qb)
{
    const int t    = threadIdx.x;
    const int lane = t & 63;
    const int w    = t >> 6;
    const int q    = lane >> 4;
    const int n15  = lane & 15;
    const int chb  = 64 * w;

    bf16x8 afrag[4][4];
    #pragma unroll
    for (int mtl = 0; mtl < 4; ++mtl) {
        const int ch = chb + 16 * mtl + n15;
        const float* wcol = (ch < 128) ? (W1 + ch) : (W1 + 128 * 128 + (ch - 128));
        #pragma unroll
        for (int ks = 0; ks < 4; ++ks)
            #pragma unroll
            for (int j = 0; j < 8; ++j)
                afrag[mtl][ks][j] = f2bf(wcol[(size_t)(32 * ks + 8 * q + j) * 128]);
    }
    float b1r[16];
    #pragma unroll
    for (int mtl = 0; mtl < 4; ++mtl)
        #pragma unroll
        for (int r = 0; r < 4; ++r) {
            const int ch = chb + 16 * mtl + 4 * q + r;
            b1r[mtl * 4 + r] = (ch < 128) ? b1[ch] : 0.0f;
        }

    unsigned short* tbase = (w < 2) ? Pb : Qb;
    const int mtb = 4 * (w & 1);   // mt base within table

    for (int tile = blockIdx.x; tile < N_NODES / 16; tile += gridDim.x) {
        const int n0 = tile * 16;
        const float* xrow = x + (size_t)(n0 + n15) * 128;

        bf16x8 bfr[4];
        #pragma unroll
        for (int ks = 0; ks < 4; ++ks) {
            f32x4 xa = *(const f32x4*)(xrow + 32 * ks + 8 * q);
            f32x4 xb = *(const f32x4*)(xrow + 32 * ks + 8 * q + 4);
            u32x4 bu;
            bu[0] = cvtpk(xa[0], xa[1]);
            bu[1] = cvtpk(xa[2], xa[3]);
            bu[2] = cvtpk(xb[0], xb[1]);
            bu[3] = cvtpk(xb[2], xb[3]);
            bfr[ks] = __builtin_bit_cast(bf16x8, bu);
        }
        #pragma unroll
        for (int mtl = 0; mtl < 4; ++mtl) {
            f32x4 acc = {0.f, 0.f, 0.f, 0.f};
            #pragma unroll
            for (int ks = 0; ks < 4; ++ks)
                acc = __builtin_amdgcn_mfma_f32_16x16x32_bf16(afrag[mtl][ks], bfr[ks], acc, 0, 0, 0);
            unsigned* dst = (unsigned*)(tbase + (size_t)(n0 + n15) * 128 + q * 32 + (mtb + mtl) * 4);
            dst[0] = cvtpk(acc[0] + b1r[mtl * 4 + 0], acc[1] + b1r[mtl * 4 + 1]);
            dst[1] = cvtpk(acc[2] + b1r[mtl * 4 + 2], acc[3] + b1r[mtl * 4 + 3]);
        }
    }
}

// ---------------------------------------------------------------------------
// Edge kernel v4: DEEP gather pipeline.
//   idx/ef prefetched 3 tiles ahead; P/Q gathers double-buffered so each
//   gather set has ~1.6 iterations of latency cover (vs ~0.3 before).
//   Loop unrolled x2 so buffer roles are compile-time (no dynamic indexing).
//   Occupancy deliberately traded (3 waves/SIMD) for in-flight depth —
//   R3 proved wave count is non-binding.
// ---------------------------------------------------------------------------
__global__ __launch_bounds__(256, 3) void edge_mfma(
    const int* __restrict__ ei, const float* __restrict__ ef,
    const float* __restrict__ W1, const float* __restrict__ W2,
    const float* __restrict__ b2, const float* __restrict__ W3,
    const float* __restrict__ b3, const unsigned short* __restrict__ Pb,
    const unsigned short* __restrict__ Qb, float* __restrict__ out)
{
    __shared__ unsigned short w2s[16 * 64 * 8];   // 16 frags x 64 lanes x 16B = 16 KiB
    __shared__ unsigned short a1s[8 * 64 * 8];    // 8 frags x 64 lanes x 16B  =  8 KiB
    const int t    = threadIdx.x;
    const int lane = t & 63;
    const int w    = t >> 6;
    const int q    = lane >> 4;
    const int n15  = lane & 15;

    // stage W1c^T frags (edge-feature slice): wave w writes mt = 2w, 2w+1
    #pragma unroll
    for (int i = 0; i < 2; ++i) {
        const int mt = 2 * w + i;
        bf16x8 f;
        #pragma unroll
        for (int j = 0; j < 8; ++j)
            f[j] = f2bf(W1[(size_t)(256 + 8 * q + j) * 128 + 16 * mt + n15]);
        *(bf16x8*)&a1s[(mt * 64 + lane) * 8] = f;
    }

    // stage W2^T frags in PERMUTED k-order: wave w writes mt2 = w
    // chunk ks, lane q, reg j  <->  channel 32ks + (j<4 ? 4q+j : 16+4q+j-4)
    {
        const int mt2 = w;
        #pragma unroll
        for (int ks = 0; ks < 4; ++ks) {
            bf16x8 f;
            #pragma unroll
            for (int j = 0; j < 8; ++j) {
                const int ch = 32 * ks + ((j < 4) ? (4 * q + j) : (16 + 4 * q + (j - 4)));
                f[j] = f2bf(W2[(size_t)ch * 64 + 16 * mt2 + n15]);
            }
            *(bf16x8*)&w2s[(((mt2 << 2) | ks) * 64 + lane) * 8] = f;
        }
    }

    // b2 / W3 packed as bf16 pairs (low = b2, high = W3)
    unsigned b2w3[16];
    #pragma unroll
    for (int mt2 = 0; mt2 < 4; ++mt2)
        #pragma unroll
        for (int r = 0; r < 4; ++r) {
            const int ch = 16 * mt2 + 4 * q + r;
            b2w3[mt2 * 4 + r] = (unsigned)(unsigned short)f2bf(b2[ch])
                              | ((unsigned)(unsigned short)f2bf(W3[ch]) << 16);
        }
    const float b3v = b3[0];

    __syncthreads();   // a1s/w2s visible to all waves (only barrier in the kernel)

    const int nTiles  = N_EDGES / 16;          // 62500
    const int wid     = blockIdx.x * 4 + w;
    const int wstride = gridDim.x * 4;
    if (wid >= nTiles) return;

    // ---- pipeline state ----
    // t0: compute this iteration (ef ready, gathers ready in current buffer)
    // t1: next (ef ready, gathers in flight in other buffer)
    // t2: next-next (idx/ef in flight; gathers issued THIS iteration)
    int t0 = wid, t1 = t0 + wstride, t2 = t1 + wstride;
    bool h1 = t1 < nTiles, h2 = t2 < nTiles;

    int oi0, di0, oi1, di1, oi2, di2;
    f32x4 ea0, eb0, ea1, eb1, ea2, eb2;
    {
        const int e0 = t0 * 16;
        oi0 = ei[e0 + n15];
        di0 = ei[N_EDGES + e0 + n15];
        ea0 = *(const f32x4*)(ef + (size_t)(e0 + n15) * 32 + 8 * q);
        eb0 = *(const f32x4*)(ef + (size_t)(e0 + n15) * 32 + 8 * q + 4);
    }
    oi1 = oi0; di1 = di0; ea1 = ea0; eb1 = eb0;
    if (h1) {
        const int e1 = t1 * 16;
        oi1 = ei[e1 + n15];
        di1 = ei[N_EDGES + e1 + n15];
        ea1 = *(const f32x4*)(ef + (size_t)(e1 + n15) * 32 + 8 * q);
        eb1 = *(const f32x4*)(ef + (size_t)(e1 + n15) * 32 + 8 * q + 4);
    }
    oi2 = oi1; di2 = di1; ea2 = ea1; eb2 = eb1;
    if (h2) {
        const int e2 = t2 * 16;
        oi2 = ei[e2 + n15];
        di2 = ei[N_EDGES + e2 + n15];
        ea2 = *(const f32x4*)(ef + (size_t)(e2 + n15) * 32 + 8 * q);
        eb2 = *(const f32x4*)(ef + (size_t)(e2 + n15) * 32 + 8 * q + 4);
    }

    bf16x8 pvbA[4], qvbA[4], pvbB[4], qvbB[4];
    {
        const unsigned short* prow = Pb + (size_t)oi0 * 128 + q * 32;
        const unsigned short* qrow = Qb + (size_t)di0 * 128 + q * 32;
        #pragma unroll
        for (int c = 0; c < 4; ++c) {
            pvbA[c] = *(const bf16x8*)(prow + 8 * c);
            qvbA[c] = *(const bf16x8*)(qrow + 8 * c);
        }
    }
    if (h1) {
        const unsigned short* prow = Pb + (size_t)oi1 * 128 + q * 32;
        const unsigned short* qrow = Qb + (size_t)di1 * 128 + q * 32;
        #pragma unroll
        for (int c = 0; c < 4; ++c) {
            pvbB[c] = *(const bf16x8*)(prow + 8 * c);
            qvbB[c] = *(const bf16x8*)(qrow + 8 * c);
        }
    } else {
        #pragma unroll
        for (int c = 0; c < 4; ++c) { pvbB[c] = pvbA[c]; qvbB[c] = qvbA[c]; }
    }

    // One pipeline step: compute tile t0 from (PC,QC), prefetch idx/ef for
    // t3, and refill (PC,QC) with gathers for t2 (consumed 2 steps later).
#define STEP(PC, QC)                                                           \
    {                                                                          \
        u32x4 befu;                                                            \
        befu[0] = cvtpk(ea0[0], ea0[1]);                                       \
        befu[1] = cvtpk(ea0[2], ea0[3]);                                       \
        befu[2] = cvtpk(eb0[0], eb0[1]);                                       \
        befu[3] = cvtpk(eb0[2], eb0[3]);                                       \
        const bf16x8 bef = __builtin_bit_cast(bf16x8, befu);                   \
        const int  t3 = t2 + wstride;                                          \
        const bool h3 = h2 && (t3 < nTiles);                                   \
        int oi3 = oi2, di3 = di2;                                              \
        f32x4 ea3 = ea2, eb3 = eb2;                                            \
        if (h3) {                                                              \
            const int e3 = t3 * 16;                                            \
            oi3 = ei[e3 + n15];                                                \
            di3 = ei[N_EDGES + e3 + n15];                                      \
            ea3 = *(const f32x4*)(ef + (size_t)(e3 + n15) * 32 + 8 * q);       \
            eb3 = *(const f32x4*)(ef + (size_t)(e3 + n15) * 32 + 8 * q + 4);   \
        }                                                                      \
        /* phase 1: 8 MFMA + epilogue, consumes PC/QC (gathered 2 steps ago) */\
        u32x4 hfu[4];                                                          \
        _Pragma("unroll")                                                      \
        for (int mt = 0; mt < 8; ++mt) {                                       \
            const bf16x8 a1f = *(const bf16x8*)&a1s[(mt * 64 + lane) * 8];     \
            f32x4 z = {0.f, 0.f, 0.f, 0.f};                                    \
            f32x4 hh = __builtin_amdgcn_mfma_f32_16x16x32_bf16(a1f, bef, z, 0, 0, 0); \
            const int c = mt >> 1, off = (mt & 1) * 4;                         \
            float v0 = lrelu(hh[0] + bf2f((unsigned short)PC[c][off + 0]) + bf2f((unsigned short)QC[c][off + 0])); \
            float v1 = lrelu(hh[1] + bf2f((unsigned short)PC[c][off + 1]) + bf2f((unsigned short)QC[c][off + 1])); \
            float v2 = lrelu(hh[2] + bf2f((unsigned short)PC[c][off + 2]) + bf2f((unsigned short)QC[c][off + 2])); \
            float v3 = lrelu(hh[3] + bf2f((unsigned short)PC[c][off + 3]) + bf2f((unsigned short)QC[c][off + 3])); \
            hfu[mt >> 1][(mt & 1) * 2 + 0] = cvtpk(v0, v1);                    \
            hfu[mt >> 1][(mt & 1) * 2 + 1] = cvtpk(v2, v3);                    \
        }                                                                      \
        /* PC/QC now dead: refill with gathers for t2 (idx ready since last  */\
        /* step) -> ~1.6 iterations of cover before consumption              */\
        if (h2) {                                                              \
            const unsigned short* prow = Pb + (size_t)oi2 * 128 + q * 32;      \
            const unsigned short* qrow = Qb + (size_t)di2 * 128 + q * 32;      \
            _Pragma("unroll")                                                  \
            for (int c2 = 0; c2 < 4; ++c2) {                                   \
                PC[c2] = *(const bf16x8*)(prow + 8 * c2);                      \
                QC[c2] = *(const bf16x8*)(qrow + 8 * c2);                      \
            }                                                                  \
        }                                                                      \
        /* phase 2: 16 MFMA, B-operand straight from hfu registers */          \
        f32x4 acc2[4] = {{0.f,0.f,0.f,0.f},{0.f,0.f,0.f,0.f},{0.f,0.f,0.f,0.f},{0.f,0.f,0.f,0.f}}; \
        _Pragma("unroll")                                                      \
        for (int ks = 0; ks < 4; ++ks) {                                       \
            const bf16x8 hfrag = __builtin_bit_cast(bf16x8, hfu[ks]);          \
            _Pragma("unroll")                                                  \
            for (int mt2 = 0; mt2 < 4; ++mt2) {                                \
                const bf16x8 a2f = *(const bf16x8*)&w2s[(((mt2 << 2) | ks) * 64 + lane) * 8]; \
                acc2[mt2] = __builtin_amdgcn_mfma_f32_16x16x32_bf16(a2f, hfrag, acc2[mt2], 0, 0, 0); \
            }                                                                  \
        }                                                                      \
        /* phase 3: bias, leaky, dot W3, 4-way lane reduce */                  \
        float s = 0.0f;                                                        \
        _Pragma("unroll")                                                      \
        for (int mt2 = 0; mt2 < 4; ++mt2)                                      \
            _Pragma("unroll")                                                  \
            for (int r = 0; r < 4; ++r) {                                      \
                const unsigned u = b2w3[mt2 * 4 + r];                          \
                float v = acc2[mt2][r] + bf2f((unsigned short)(u & 0xffffu));  \
                v = lrelu(v);                                                  \
                s += v * __uint_as_float(u & 0xffff0000u);                     \
            }                                                                  \
        s += __shfl_xor(s, 16);                                                \
        s += __shfl_xor(s, 32);                                                \
        if (q == 0) out[t0 * 16 + n15] = s + b3v;                              \
        if (!h1) goto done;                                                    \
        t0 = t1; t1 = t2; t2 = t3;                                             \
        h1 = h2; h2 = h3;                                                      \
        ea0 = ea1; eb0 = eb1; ea1 = ea2; eb1 = eb2; ea2 = ea3; eb2 = eb3;      \
        oi2 = oi3; di2 = di3;                                                  \
    }

    for (;;) {
        STEP(pvbA, qvbA);   // even tiles live in buffer A
        STEP(pvbB, qvbB);   // odd tiles live in buffer B
    }
done: ;
#undef STEP
}

extern "C" void kernel_launch(void* const* d_in, const int* in_sizes, int n_in,
                              void* d_out, int out_size, void* d_ws, size_t ws_size,
                              hipStream_t stream) {
    const float* x   = (const float*)d_in[0];
    const int*   ei  = (const int*)d_in[1];
    const float* ef  = (const float*)d_in[2];
    const float* W1  = (const float*)d_in[3];
    const float* b1  = (const float*)d_in[4];
    const float* W2  = (const float*)d_in[5];
    const float* b2  = (const float*)d_in[6];
    const float* W3  = (const float*)d_in[7];
    const float* b3  = (const float*)d_in[8];
    float*       out = (float*)d_out;

    unsigned short* Pb = (unsigned short*)d_ws;           // [N_NODES][128] bf16 swizzled (+b1)
    unsigned short* Qb = Pb + (size_t)N_NODES * 128;      // [N_NODES][128] bf16 swizzled
    // ws usage: 51.2 MB

    precompute_mfma<<<2048, 256, 0, stream>>>(x, W1, b1, Pb, Qb);
    edge_mfma<<<768, 256, 0, stream>>>(ei, ef, W1, W2, b2, W3, b3, Pb, Qb, out);
}

// Round 5
// 340.509 us; speedup vs baseline: 1.0471x; 1.0471x over previous
//
#include <hip/hip_runtime.h>

#define N_NODES 100000
#define N_EDGES 1000000

typedef __attribute__((ext_vector_type(8))) short bf16x8;
typedef __attribute__((ext_vector_type(4))) float f32x4;
typedef __attribute__((ext_vector_type(4))) unsigned u32x4;

static __device__ __forceinline__ short f2bf(float f) {
    unsigned u = __float_as_uint(f);
    u = (u + 0x7fffu + ((u >> 16) & 1u)) >> 16;
    return (short)u;
}
static __device__ __forceinline__ float bf2f(unsigned short s) {
    return __uint_as_float(((unsigned)s) << 16);
}
static __device__ __forceinline__ float lrelu(float x) {
    return fmaxf(x, 0.01f * x);   // 0.01x > x iff x < 0
}
// packed f32->bf16 (RNE)
static __device__ __forceinline__ unsigned cvtpk(float lo, float hi) {
    unsigned r;
    asm("v_cvt_pk_bf16_f32 %0, %1, %2" : "=v"(r) : "v"(lo), "v"(hi));
    return r;
}
// non-temporal helpers: single-use streams must not evict the P/Q tables from L3
static __device__ __forceinline__ f32x4 ldnt_f4(const float* p) {
    return __builtin_nontemporal_load((const f32x4*)p);
}
static __device__ __forceinline__ int ldnt_i(const int* p) {
    return __builtin_nontemporal_load(p);
}

// ---------------------------------------------------------------------------
// Precompute: P/Q as bf16 in gather-swizzled layout.
// Grid 512 (was 2048): the per-block W1-fragment setup (~128 strided loads)
// is redundant per block; 12 tiles/block amortizes it 4x better.
// x is read once -> non-temporal (keeps L3 clean for the edge kernel).
// ---------------------------------------------------------------------------
__global__ __launch_bounds__(256) void precompute_mfma(
    const float* __restrict__ x, const float* __restrict__ W1,
    const float* __restrict__ b1, unsigned short* __restrict__ Pb,
    unsigned short* __restrict__ Qb)
{
    const int t    = threadIdx.x;
    const int lane = t & 63;
    const int w    = t >> 6;
    const int q    = lane >> 4;
    const int n15  = lane & 15;
    const int chb  = 64 * w;

    bf16x8 afrag[4][4];
    #pragma unroll
    for (int mtl = 0; mtl < 4; ++mtl) {
        const int ch = chb + 16 * mtl + n15;
        const float* wcol = (ch < 128) ? (W1 + ch) : (W1 + 128 * 128 + (ch - 128));
        #pragma unroll
        for (int ks = 0; ks < 4; ++ks)
            #pragma unroll
            for (int j = 0; j < 8; ++j)
                afrag[mtl][ks][j] = f2bf(wcol[(size_t)(32 * ks + 8 * q + j) * 128]);
    }
    float b1r[16];
    #pragma unroll
    for (int mtl = 0; mtl < 4; ++mtl)
        #pragma unroll
        for (int r = 0; r < 4; ++r) {
            const int ch = chb + 16 * mtl + 4 * q + r;
            b1r[mtl * 4 + r] = (ch < 128) ? b1[ch] : 0.0f;
        }

    unsigned short* tbase = (w < 2) ? Pb : Qb;
    const int mtb = 4 * (w & 1);   // mt base within table

    for (int tile = blockIdx.x; tile < N_NODES / 16; tile += gridDim.x) {
        const int n0 = tile * 16;
        const float* xrow = x + (size_t)(n0 + n15) * 128;

        bf16x8 bfr[4];
        #pragma unroll
        for (int ks = 0; ks < 4; ++ks) {
            f32x4 xa = ldnt_f4(xrow + 32 * ks + 8 * q);
            f32x4 xb = ldnt_f4(xrow + 32 * ks + 8 * q + 4);
            u32x4 bu;
            bu[0] = cvtpk(xa[0], xa[1]);
            bu[1] = cvtpk(xa[2], xa[3]);
            bu[2] = cvtpk(xb[0], xb[1]);
            bu[3] = cvtpk(xb[2], xb[3]);
            bfr[ks] = __builtin_bit_cast(bf16x8, bu);
        }
        #pragma unroll
        for (int mtl = 0; mtl < 4; ++mtl) {
            f32x4 acc = {0.f, 0.f, 0.f, 0.f};
            #pragma unroll
            for (int ks = 0; ks < 4; ++ks)
                acc = __builtin_amdgcn_mfma_f32_16x16x32_bf16(afrag[mtl][ks], bfr[ks], acc, 0, 0, 0);
            unsigned* dst = (unsigned*)(tbase + (size_t)(n0 + n15) * 128 + q * 32 + (mtb + mtl) * 4);
            dst[0] = cvtpk(acc[0] + b1r[mtl * 4 + 0], acc[1] + b1r[mtl * 4 + 1]);
            dst[1] = cvtpk(acc[2] + b1r[mtl * 4 + 2], acc[3] + b1r[mtl * 4 + 3]);
        }
    }
}

// ---------------------------------------------------------------------------
// Edge kernel v5: clean v3 structure (spill-free, 64 VGPR) + non-temporal
// policy on single-use streams (ei, ef, out). P/Q gathers stay cached so
// the 51.2 MB tables can live in L3 without being thrashed by the 128 MB
// ef stream (R4 theory: FETCH_SIZE 302 vs 191 MB ideal = L3 eviction).
// ---------------------------------------------------------------------------
__global__ __launch_bounds__(256, 3) void edge_mfma(
    const int* __restrict__ ei, const float* __restrict__ ef,
    const float* __restrict__ W1, const float* __restrict__ W2,
    const float* __restrict__ b2, const float* __restrict__ W3,
    const float* __restrict__ b3, const unsigned short* __restrict__ Pb,
    const unsigned short* __restrict__ Qb, float* __restrict__ out)
{
    __shared__ unsigned short w2s[16 * 64 * 8];   // 16 frags x 64 lanes x 16B = 16 KiB
    __shared__ unsigned short a1s[8 * 64 * 8];    // 8 frags x 64 lanes x 16B  =  8 KiB
    const int t    = threadIdx.x;
    const int lane = t & 63;
    const int w    = t >> 6;
    const int q    = lane >> 4;
    const int n15  = lane & 15;

    // stage W1c^T frags (edge-feature slice): wave w writes mt = 2w, 2w+1
    #pragma unroll
    for (int i = 0; i < 2; ++i) {
        const int mt = 2 * w + i;
        bf16x8 f;
        #pragma unroll
        for (int j = 0; j < 8; ++j)
            f[j] = f2bf(W1[(size_t)(256 + 8 * q + j) * 128 + 16 * mt + n15]);
        *(bf16x8*)&a1s[(mt * 64 + lane) * 8] = f;
    }

    // stage W2^T frags in PERMUTED k-order: wave w writes mt2 = w
    // chunk ks, lane q, reg j  <->  channel 32ks + (j<4 ? 4q+j : 16+4q+j-4)
    {
        const int mt2 = w;
        #pragma unroll
        for (int ks = 0; ks < 4; ++ks) {
            bf16x8 f;
            #pragma unroll
            for (int j = 0; j < 8; ++j) {
                const int ch = 32 * ks + ((j < 4) ? (4 * q + j) : (16 + 4 * q + (j - 4)));
                f[j] = f2bf(W2[(size_t)ch * 64 + 16 * mt2 + n15]);
            }
            *(bf16x8*)&w2s[(((mt2 << 2) | ks) * 64 + lane) * 8] = f;
        }
    }

    // b2 / W3 packed as bf16 pairs (low = b2, high = W3)
    unsigned b2w3[16];
    #pragma unroll
    for (int mt2 = 0; mt2 < 4; ++mt2)
        #pragma unroll
        for (int r = 0; r < 4; ++r) {
            const int ch = 16 * mt2 + 4 * q + r;
            b2w3[mt2 * 4 + r] = (unsigned)(unsigned short)f2bf(b2[ch])
                              | ((unsigned)(unsigned short)f2bf(W3[ch]) << 16);
        }
    const float b3v = b3[0];

    __syncthreads();   // a1s/w2s visible to all waves (only barrier in the kernel)

    const int nTiles  = N_EDGES / 16;          // 62500
    const int wid     = blockIdx.x * 4 + w;
    const int wstride = gridDim.x * 4;
    if (wid >= nTiles) return;

    // ---- prologue: generations 0 (idx+ef+gather) and 1 (idx+ef) ----
    int tile0 = wid;
    int tile1 = tile0 + wstride;
    bool have1 = tile1 < nTiles;

    int oi0, di0; f32x4 ea0, eb0;
    {
        const int e0 = tile0 * 16;
        oi0 = ldnt_i(&ei[e0 + n15]);
        di0 = ldnt_i(&ei[N_EDGES + e0 + n15]);
        ea0 = ldnt_f4(ef + (size_t)(e0 + n15) * 32 + 8 * q);
        eb0 = ldnt_f4(ef + (size_t)(e0 + n15) * 32 + 8 * q + 4);
    }
    int oi1 = 0, di1 = 0; f32x4 ea1 = ea0, eb1 = eb0;
    if (have1) {
        const int e1 = tile1 * 16;
        oi1 = ldnt_i(&ei[e1 + n15]);
        di1 = ldnt_i(&ei[N_EDGES + e1 + n15]);
        ea1 = ldnt_f4(ef + (size_t)(e1 + n15) * 32 + 8 * q);
        eb1 = ldnt_f4(ef + (size_t)(e1 + n15) * 32 + 8 * q + 4);
    }
    bf16x8 pvb[4], qvb[4];
    {
        const unsigned short* prow = Pb + (size_t)oi0 * 128 + q * 32;
        const unsigned short* qrow = Qb + (size_t)di0 * 128 + q * 32;
        #pragma unroll
        for (int c = 0; c < 4; ++c) {
            pvb[c] = *(const bf16x8*)(prow + 8 * c);
            qvb[c] = *(const bf16x8*)(qrow + 8 * c);
        }
    }

    while (true) {
        // convert current ef to B-frag
        u32x4 befu;
        befu[0] = cvtpk(ea0[0], ea0[1]);
        befu[1] = cvtpk(ea0[2], ea0[3]);
        befu[2] = cvtpk(eb0[0], eb0[1]);
        befu[3] = cvtpk(eb0[2], eb0[3]);
        const bf16x8 bef = __builtin_bit_cast(bf16x8, befu);

        // issue generation-2 idx + ef loads (consumed next-next iteration)
        const int  tile2 = tile1 + wstride;
        const bool have2 = have1 && (tile2 < nTiles);
        int oi2 = oi1, di2 = di1; f32x4 ea2 = ea1, eb2 = eb1;
        if (have2) {
            const int e2 = tile2 * 16;
            oi2 = ldnt_i(&ei[e2 + n15]);
            di2 = ldnt_i(&ei[N_EDGES + e2 + n15]);
            ea2 = ldnt_f4(ef + (size_t)(e2 + n15) * 32 + 8 * q);
            eb2 = ldnt_f4(ef + (size_t)(e2 + n15) * 32 + 8 * q + 4);
        }

        // ---- phase 1: 8 MFMA + epilogue -> hfu (registers, no LDS) ----
        u32x4 hfu[4];
        #pragma unroll
        for (int mt = 0; mt < 8; ++mt) {
            const bf16x8 a1f = *(const bf16x8*)&a1s[(mt * 64 + lane) * 8];
            f32x4 z = {0.f, 0.f, 0.f, 0.f};
            f32x4 h = __builtin_amdgcn_mfma_f32_16x16x32_bf16(a1f, bef, z, 0, 0, 0);
            const int c = mt >> 1, off = (mt & 1) * 4;
            float v0 = lrelu(h[0] + bf2f((unsigned short)pvb[c][off + 0]) + bf2f((unsigned short)qvb[c][off + 0]));
            float v1 = lrelu(h[1] + bf2f((unsigned short)pvb[c][off + 1]) + bf2f((unsigned short)qvb[c][off + 1]));
            float v2 = lrelu(h[2] + bf2f((unsigned short)pvb[c][off + 2]) + bf2f((unsigned short)qvb[c][off + 2]));
            float v3 = lrelu(h[3] + bf2f((unsigned short)pvb[c][off + 3]) + bf2f((unsigned short)qvb[c][off + 3]));
            hfu[mt >> 1][(mt & 1) * 2 + 0] = cvtpk(v0, v1);
            hfu[mt >> 1][(mt & 1) * 2 + 1] = cvtpk(v2, v3);
        }

        // pvb/qvb now dead: issue next tile's gathers (indices loaded a full
        // iteration ago -> no address-dependency stall here). Cached (L3).
        if (have1) {
            const unsigned short* prow = Pb + (size_t)oi1 * 128 + q * 32;
            const unsigned short* qrow = Qb + (size_t)di1 * 128 + q * 32;
            #pragma unroll
            for (int c = 0; c < 4; ++c) {
                pvb[c] = *(const bf16x8*)(prow + 8 * c);
                qvb[c] = *(const bf16x8*)(qrow + 8 * c);
            }
        }

        // ---- phase 2: 16 MFMA, B-operand straight from hfu registers ----
        f32x4 acc2[4] = {{0.f,0.f,0.f,0.f},{0.f,0.f,0.f,0.f},{0.f,0.f,0.f,0.f},{0.f,0.f,0.f,0.f}};
        #pragma unroll
        for (int ks = 0; ks < 4; ++ks) {
            const bf16x8 hfrag = __builtin_bit_cast(bf16x8, hfu[ks]);
            #pragma unroll
            for (int mt2 = 0; mt2 < 4; ++mt2) {
                const bf16x8 a2f = *(const bf16x8*)&w2s[(((mt2 << 2) | ks) * 64 + lane) * 8];
                acc2[mt2] = __builtin_amdgcn_mfma_f32_16x16x32_bf16(a2f, hfrag, acc2[mt2], 0, 0, 0);
            }
        }

        // ---- phase 3: bias, leaky, dot W3, 4-way lane reduce ----
        float s = 0.0f;
        #pragma unroll
        for (int mt2 = 0; mt2 < 4; ++mt2)
            #pragma unroll
            for (int r = 0; r < 4; ++r) {
                const unsigned u = b2w3[mt2 * 4 + r];
                float v = acc2[mt2][r] + bf2f((unsigned short)(u & 0xffffu));
                v = lrelu(v);
                s += v * __uint_as_float(u & 0xffff0000u);
            }
        s += __shfl_xor(s, 16);
        s += __shfl_xor(s, 32);
        if (q == 0) __builtin_nontemporal_store(s + b3v, &out[tile0 * 16 + n15]);

        if (!have1) break;
        tile0 = tile1; tile1 = tile2; have1 = have2;
        oi1 = oi2; di1 = di2;
        ea0 = ea1; eb0 = eb1; ea1 = ea2; eb1 = eb2;
    }
}

extern "C" void kernel_launch(void* const* d_in, const int* in_sizes, int n_in,
                              void* d_out, int out_size, void* d_ws, size_t ws_size,
                              hipStream_t stream) {
    const float* x   = (const float*)d_in[0];
    const int*   ei  = (const int*)d_in[1];
    const float* ef  = (const float*)d_in[2];
    const float* W1  = (const float*)d_in[3];
    const float* b1  = (const float*)d_in[4];
    const float* W2  = (const float*)d_in[5];
    const float* b2  = (const float*)d_in[6];
    const float* W3  = (const float*)d_in[7];
    const float* b3  = (const float*)d_in[8];
    float*       out = (float*)d_out;

    unsigned short* Pb = (unsigned short*)d_ws;           // [N_NODES][128] bf16 swizzled (+b1)
    unsigned short* Qb = Pb + (size_t)N_NODES * 128;      // [N_NODES][128] bf16 swizzled
    // ws usage: 51.2 MB

    precompute_mfma<<<512, 256, 0, stream>>>(x, W1, b1, Pb, Qb);
    edge_mfma<<<1536, 256, 0, stream>>>(ei, ef, W1, W2, b2, W3, b3, Pb, Qb, out);
}